// Round 5
// baseline (127.337 us; speedup 1.0000x reference)
//
#include <hip/hip_runtime.h>
#include <stdint.h>

#define EPS_BN 1e-5f

#define C 256
#define H 28
#define W 28
#define R196 196
#define M_TOT 12544
#define K1 2304

typedef __attribute__((ext_vector_type(8))) short bf16x8;
typedef __attribute__((ext_vector_type(4))) float f32x4;
typedef __attribute__((ext_vector_type(4))) unsigned short u16x4;
typedef unsigned short ushort_t;

__device__ __forceinline__ unsigned short sgn_bf16(float v) {
    return v > 0.f ? (unsigned short)0x3F80
                   : (v < 0.f ? (unsigned short)0xBF80 : (unsigned short)0);
}

__device__ __forceinline__ void gload16(const void* g, void* l) {
    __builtin_amdgcn_global_load_lds(
        (const __attribute__((address_space(1))) void*)g,
        (__attribute__((address_space(3))) void*)l, 16, 0, 0);
}

// ---------------------------------------------------------------------------
// Kernel 1: weight prep (unchanged).
// ---------------------------------------------------------------------------
__global__ void prep_weights(
    const float* __restrict__ w1,
    const float* __restrict__ bn1_g, const float* __restrict__ bn1_b,
    const float* __restrict__ bn1_m, const float* __restrict__ bn1_v,
    const float* __restrict__ w21,
    const float* __restrict__ bn21_g, const float* __restrict__ bn21_b,
    const float* __restrict__ bn21_m, const float* __restrict__ bn21_v,
    const float* __restrict__ w22,
    const float* __restrict__ bn22_g, const float* __restrict__ bn22_b,
    const float* __restrict__ bn22_m, const float* __restrict__ bn22_v,
    unsigned short* __restrict__ bw1, unsigned short* __restrict__ bw2,
    float* __restrict__ alpha1, float* __restrict__ beta1,
    float* __restrict__ alpha2, float* __restrict__ beta2)
{
    __shared__ float red[256];
    const int bid = blockIdx.x;
    const int t = threadIdx.x;

    if (bid < 256) {
        const int oc = bid;
        const float* w = w1 + oc * K1;
        float s = 0.f;
        for (int i = t; i < K1; i += 256) s += fabsf(w[i]);
        red[t] = s; __syncthreads();
        for (int o = 128; o > 0; o >>= 1) {
            if (t < o) red[t] += red[t + o];
            __syncthreads();
        }
        const float scale = red[0] * (1.f / (float)K1);
        if (t == 0) {
            const float inv = bn1_g[oc] * rsqrtf(bn1_v[oc] + EPS_BN);
            alpha1[oc] = scale * inv;
            beta1[oc]  = bn1_b[oc] - bn1_m[oc] * inv;
        }
        for (int i = t; i < K1; i += 256) {
            const int ic = i / 9, tap = i % 9;
            bw1[(oc * 9 + tap) * 256 + ic] = sgn_bf16(w[i]);
        }
    } else {
        const bool br2 = (bid >= 512);
        const int oc = (bid - 256) & 255;
        const float* w = (br2 ? w22 : w21) + oc * 256;
        red[t] = fabsf(w[t]); __syncthreads();
        for (int o = 128; o > 0; o >>= 1) {
            if (t < o) red[t] += red[t + o];
            __syncthreads();
        }
        const float scale = red[0] * (1.f / 256.f);
        const int n = oc + (br2 ? 256 : 0);
        if (t == 0) {
            const float g = br2 ? bn22_g[oc] : bn21_g[oc];
            const float b = br2 ? bn22_b[oc] : bn21_b[oc];
            const float m = br2 ? bn22_m[oc] : bn21_m[oc];
            const float v = br2 ? bn22_v[oc] : bn21_v[oc];
            const float inv = g * rsqrtf(v + EPS_BN);
            alpha2[n] = scale * inv;
            beta2[n]  = b - m * inv;
        }
        bw2[n * 256 + t] = sgn_bf16(w[t]);
    }
}

// ---------------------------------------------------------------------------
// Kernel 2: fused sign(x+bias) -> a1p AND 2x2 avgpool (unchanged).
// ---------------------------------------------------------------------------
__global__ __launch_bounds__(256) void sign_pool(
    const float* __restrict__ x, const float* __restrict__ bias,
    ushort_t* __restrict__ a1p, float* __restrict__ pool)
{
    __shared__ float lx[2][256][29];
    const int bo = blockIdx.x;               // b*14 + oh
    const int b = bo / 14, oh = bo % 14;
    const int t = threadIdx.x;
    const float* xb = x + (size_t)(b * 256) * 784 + (2 * oh) * 28;

    for (int idx = t; idx < 2 * 28 * 256; idx += 256) {
        const int row = idx / 7168;
        const int rem = idx - row * 7168;
        const int c = rem / 28, iw = rem % 28;
        lx[row][c][iw] = xb[c * 784 + row * 28 + iw];
    }
    __syncthreads();

#pragma unroll
    for (int row = 0; row < 2; ++row) {
        ushort_t* orow = a1p + (size_t)((b * 30 + 2 * oh + row + 1) * 30) * 256;
        for (int idx = t; idx < 28 * 256; idx += 256) {
            const int c = idx & 255, iw = idx >> 8;
            orow[(iw + 1) * 256 + c] = sgn_bf16(lx[row][c][iw] + bias[c]);
        }
        orow[t] = 0;
        orow[29 * 256 + t] = 0;
    }

    for (int idx = t; idx < 256 * 14; idx += 256) {
        const int c = idx / 14, ow = idx % 14;
        pool[(size_t)(b * 256 + c) * 196 + oh * 14 + ow] =
            0.25f * (lx[0][c][2 * ow] + lx[0][c][2 * ow + 1] +
                     lx[1][c][2 * ow] + lx[1][c][2 * ow + 1]);
    }

    if (oh == 0) {
        ushort_t* r0  = a1p + (size_t)(b * 900) * 256;
        ushort_t* r29 = a1p + (size_t)(b * 900 + 29 * 30) * 256;
        for (int idx = t; idx < 30 * 256; idx += 256) { r0[idx] = 0; r29[idx] = 0; }
    }
}

// ---------------------------------------------------------------------------
// Kernel 3: conv1 (3x3 s2) GEMM. BM=64 BN=64 BK=64, 784 blocks (196m x 4n),
// 4 waves (2m x 2n), wave tile 32x32. DEPTH-3 pipeline: 3 LDS buffers,
// stage(t+2) issued at top of iter t, s_waitcnt vmcnt(8) -> each stage has
// ~2 steps of flight time to land. Restage of buf (t-1)%3 is safe: its
// readers crossed the end-barrier of iter t-1.
// ---------------------------------------------------------------------------
__global__ __launch_bounds__(256) void conv1_lds(
    const ushort_t* __restrict__ a1p,   // [64][30][30][256]
    const ushort_t* __restrict__ bw1,   // [256][2304]
    const float* __restrict__ alpha1, const float* __restrict__ beta1,
    const float* __restrict__ p,
    const float* __restrict__ rsb,
    const float* __restrict__ prg, const float* __restrict__ prb,
    const float* __restrict__ prz,
    float* __restrict__ out2,
    ushort_t* __restrict__ a2)
{
    __shared__ ushort_t lA[3][64 * 64];
    __shared__ ushort_t lB[3][64 * 64];

    const int bid = blockIdx.x;
    const int wgid = (bid & 7) * 98 + (bid >> 3);   // 784 = 8*98
    const int mtile = wgid >> 2;        // 0..195 (ntile fastest -> same XCD)
    const int ntile = wgid & 3;

    const int tid = threadIdx.x;
    const int wave = tid >> 6;
    const int lane = tid & 63;
    const int col = lane & 15;
    const int krow = lane >> 4;
    const int wr = wave >> 1;
    const int wc = wave & 1;
    const int l8 = lane >> 3;
    const int s8 = lane & 7;
    const int swz = ((s8 ^ l8) << 3);   // pre-swizzled source column (elements)

    int pb[2];
#pragma unroll
    for (int i = 0; i < 2; ++i) {
        const int grow = wave * 16 + i * 8 + l8;
        const int m = mtile * 64 + grow;
        const int b = m / 196, r = m % 196;
        const int oh = r / 14, ow = r % 14;
        pb[i] = ((b * 30 + 2 * oh) * 30 + 2 * ow) * 256 + swz;
    }
    int wb[2];
#pragma unroll
    for (int i = 0; i < 2; ++i)
        wb[i] = (ntile * 64 + wave * 16 + i * 8 + l8) * K1 + swz;

    int rswz[2];
#pragma unroll
    for (int ks = 0; ks < 2; ++ks)
        rswz[ks] = ((ks * 4 + krow) ^ (col & 7)) << 4;

    f32x4 acc[2][2] = {};

    auto stage = [&](int step, int buf) {
        const int tap = step >> 2;
        const int kc0 = (step & 3) << 6;
        const int kh = tap / 3, kw = tap - kh * 3;
        const int aoff = (kh * 30 + kw) * 256 + kc0;
#pragma unroll
        for (int i = 0; i < 2; ++i)
            gload16(a1p + pb[i] + aoff, (char*)&lA[buf][0] + (wave * 16 + i * 8) * 128);
#pragma unroll
        for (int i = 0; i < 2; ++i)
            gload16(bw1 + wb[i] + step * 64, (char*)&lB[buf][0] + (wave * 16 + i * 8) * 128);
    };

    stage(0, 0);
    stage(1, 1);

    int cur = 0;
    for (int step = 0; step < 36; ++step) {
        if (step + 2 < 36) {
            int nb = cur + 2; if (nb >= 3) nb -= 3;
            stage(step + 2, nb);                             // +4 loads in flight
            asm volatile("s_waitcnt vmcnt(8)" ::: "memory"); // tile-t's 4 done
        } else if (step + 1 < 36) {
            asm volatile("s_waitcnt vmcnt(4)" ::: "memory");
        } else {
            asm volatile("s_waitcnt vmcnt(0)" ::: "memory");
        }
        __builtin_amdgcn_s_barrier();        // all waves' tile-t loads landed
        __builtin_amdgcn_sched_barrier(0);

#pragma unroll
        for (int ks = 0; ks < 2; ++ks) {
            bf16x8 bf[2], af[2];
#pragma unroll
            for (int im = 0; im < 2; ++im) {
                const int row = wr * 32 + im * 16 + col;
                bf[im] = *(const bf16x8*)((const char*)&lA[cur][0] + row * 128 + rswz[ks]);
            }
#pragma unroll
            for (int in = 0; in < 2; ++in) {
                const int row = wc * 32 + in * 16 + col;
                af[in] = *(const bf16x8*)((const char*)&lB[cur][0] + row * 128 + rswz[ks]);
            }
#pragma unroll
            for (int im = 0; im < 2; ++im)
#pragma unroll
                for (int in = 0; in < 2; ++in)
                    acc[im][in] = __builtin_amdgcn_mfma_f32_16x16x32_bf16(
                        af[in], bf[im], acc[im][in], 0, 0, 0);
        }
        __builtin_amdgcn_sched_barrier(0);
        __builtin_amdgcn_s_barrier();        // cur fully read -> restageable
        if (++cur == 3) cur = 0;
    }

#pragma unroll
    for (int im = 0; im < 2; ++im) {
        const int m = mtile * 64 + wr * 32 + im * 16 + col;
        const int b = m / 196, r = m % 196;
#pragma unroll
        for (int in = 0; in < 2; ++in) {
            const int n0 = ntile * 64 + wc * 32 + in * 16 + krow * 4;
            u16x4 spack;
#pragma unroll
            for (int j = 0; j < 4; ++j) {
                const int n = n0 + j;
                const int idx = (b * 256 + n) * 196 + r;
                float v = alpha1[n] * acc[im][in][j] + beta1[n] + p[idx];
                const float t = v - prg[n];
                const float o = (t > 0.f ? t : prb[n] * t) + prz[n];
                out2[idx] = o;
                spack[j] = sgn_bf16(o + rsb[n]);
            }
            *(u16x4*)(a2 + m * 256 + n0) = spack;
        }
    }
}

// ---------------------------------------------------------------------------
// Kernel 4: both 1x1 convs. BM=64 BN=64 K=256 (4 steps), 1568 blocks
// (196m x 8n), depth-3 pipeline (fully covers the short K-loop).
// ---------------------------------------------------------------------------
__global__ __launch_bounds__(256) void conv1x1_lds(
    const ushort_t* __restrict__ a2,
    const ushort_t* __restrict__ bw2,
    const float* __restrict__ alpha2, const float* __restrict__ beta2,
    const float* __restrict__ out2,
    const float* __restrict__ prg, const float* __restrict__ prb,
    const float* __restrict__ prz,
    float* __restrict__ out)
{
    __shared__ ushort_t lA[3][64 * 64];
    __shared__ ushort_t lB[3][64 * 64];

    const int bid = blockIdx.x;
    const int wgid = (bid & 7) * 196 + (bid >> 3);  // 1568 = 8*196
    const int mtile = wgid >> 3;        // 0..195 (ntile fastest)
    const int ntile = wgid & 7;

    const int tid = threadIdx.x;
    const int wave = tid >> 6;
    const int lane = tid & 63;
    const int col = lane & 15;
    const int krow = lane >> 4;
    const int wr = wave >> 1;
    const int wc = wave & 1;
    const int l8 = lane >> 3;
    const int s8 = lane & 7;
    const int swz = ((s8 ^ l8) << 3);

    int pb[2];
#pragma unroll
    for (int i = 0; i < 2; ++i)
        pb[i] = (mtile * 64 + wave * 16 + i * 8 + l8) * 256 + swz;
    int wb[2];
#pragma unroll
    for (int i = 0; i < 2; ++i)
        wb[i] = (ntile * 64 + wave * 16 + i * 8 + l8) * 256 + swz;

    int rswz[2];
#pragma unroll
    for (int ks = 0; ks < 2; ++ks)
        rswz[ks] = ((ks * 4 + krow) ^ (col & 7)) << 4;

    f32x4 acc[2][2] = {};

    auto stage = [&](int step, int buf) {
#pragma unroll
        for (int i = 0; i < 2; ++i)
            gload16(a2 + pb[i] + step * 64, (char*)&lA[buf][0] + (wave * 16 + i * 8) * 128);
#pragma unroll
        for (int i = 0; i < 2; ++i)
            gload16(bw2 + wb[i] + step * 64, (char*)&lB[buf][0] + (wave * 16 + i * 8) * 128);
    };

    stage(0, 0);
    stage(1, 1);

    int cur = 0;
    for (int step = 0; step < 4; ++step) {
        if (step + 2 < 4) {
            int nb = cur + 2; if (nb >= 3) nb -= 3;
            stage(step + 2, nb);
            asm volatile("s_waitcnt vmcnt(8)" ::: "memory");
        } else if (step + 1 < 4) {
            asm volatile("s_waitcnt vmcnt(4)" ::: "memory");
        } else {
            asm volatile("s_waitcnt vmcnt(0)" ::: "memory");
        }
        __builtin_amdgcn_s_barrier();
        __builtin_amdgcn_sched_barrier(0);

#pragma unroll
        for (int ks = 0; ks < 2; ++ks) {
            bf16x8 bf[2], af[2];
#pragma unroll
            for (int im = 0; im < 2; ++im) {
                const int row = wr * 32 + im * 16 + col;
                bf[im] = *(const bf16x8*)((const char*)&lA[cur][0] + row * 128 + rswz[ks]);
            }
#pragma unroll
            for (int in = 0; in < 2; ++in) {
                const int row = wc * 32 + in * 16 + col;
                af[in] = *(const bf16x8*)((const char*)&lB[cur][0] + row * 128 + rswz[ks]);
            }
#pragma unroll
            for (int im = 0; im < 2; ++im)
#pragma unroll
                for (int in = 0; in < 2; ++in)
                    acc[im][in] = __builtin_amdgcn_mfma_f32_16x16x32_bf16(
                        af[in], bf[im], acc[im][in], 0, 0, 0);
        }
        __builtin_amdgcn_sched_barrier(0);
        __builtin_amdgcn_s_barrier();
        if (++cur == 3) cur = 0;
    }

#pragma unroll
    for (int im = 0; im < 2; ++im) {
        const int m = mtile * 64 + wr * 32 + im * 16 + col;
        const int b = m / 196, r = m % 196;
#pragma unroll
        for (int in = 0; in < 2; ++in) {
#pragma unroll
            for (int j = 0; j < 4; ++j) {
                const int n = ntile * 64 + wc * 32 + in * 16 + krow * 4 + j;
                const int oc = n & 255;
                float v = alpha2[n] * acc[im][in][j] + beta2[n]
                        + out2[(b * 256 + oc) * 196 + r];
                const float t = v - prg[oc];
                out[(size_t)(b * 512 + n) * 196 + r] =
                    (t > 0.f ? t : prb[oc] * t) + prz[oc];
            }
        }
    }
}

// ---------------------------------------------------------------------------
extern "C" void kernel_launch(void* const* d_in, const int* in_sizes, int n_in,
                              void* d_out, int out_size, void* d_ws, size_t ws_size,
                              hipStream_t stream)
{
    (void)in_sizes; (void)n_in; (void)out_size; (void)ws_size;

    const float* x         = (const float*)d_in[0];
    const float* rsign_b   = (const float*)d_in[1];
    const float* w1        = (const float*)d_in[2];
    const float* bn1_g     = (const float*)d_in[3];
    const float* bn1_b     = (const float*)d_in[4];
    const float* bn1_m     = (const float*)d_in[5];
    const float* bn1_v     = (const float*)d_in[6];
    const float* w21       = (const float*)d_in[7];
    const float* bn21_g    = (const float*)d_in[8];
    const float* bn21_b    = (const float*)d_in[9];
    const float* bn21_m    = (const float*)d_in[10];
    const float* bn21_v    = (const float*)d_in[11];
    const float* w22       = (const float*)d_in[12];
    const float* bn22_g    = (const float*)d_in[13];
    const float* bn22_b    = (const float*)d_in[14];
    const float* bn22_m    = (const float*)d_in[15];
    const float* bn22_v    = (const float*)d_in[16];
    const float* pr_gamma  = (const float*)d_in[17];
    const float* pr_beta   = (const float*)d_in[18];
    const float* pr_zeta   = (const float*)d_in[19];

    char* ws = (char*)d_ws;
    size_t off = 0;
    ushort_t* a1p = (ushort_t*)(ws + off); off += (size_t)14745600 * 2;
    ushort_t* bw1 = (ushort_t*)(ws + off); off += (size_t)589824 * 2;
    ushort_t* bw2 = (ushort_t*)(ws + off); off += (size_t)131072 * 2;
    float* pool   = (float*)(ws + off);    off += (size_t)3211264 * 4;
    float* out2   = (float*)(ws + off);    off += (size_t)3211264 * 4;
    ushort_t* a2  = (ushort_t*)(ws + off); off += (size_t)3211264 * 2;
    float* alpha1 = (float*)(ws + off);    off += 1024;
    float* beta1  = (float*)(ws + off);    off += 1024;
    float* alpha2 = (float*)(ws + off);    off += 2048;
    float* beta2  = (float*)(ws + off);    off += 2048;

    prep_weights<<<768, 256, 0, stream>>>(
        w1, bn1_g, bn1_b, bn1_m, bn1_v,
        w21, bn21_g, bn21_b, bn21_m, bn21_v,
        w22, bn22_g, bn22_b, bn22_m, bn22_v,
        bw1, bw2, alpha1, beta1, alpha2, beta2);

    sign_pool<<<64 * 14, 256, 0, stream>>>(x, rsign_b, a1p, pool);

    conv1_lds<<<784, 256, 0, stream>>>(
        a1p, bw1, alpha1, beta1, pool, rsign_b,
        pr_gamma, pr_beta, pr_zeta, out2, a2);

    conv1x1_lds<<<1568, 256, 0, stream>>>(
        a2, bw2, alpha2, beta2, out2,
        pr_gamma, pr_beta, pr_zeta, (float*)d_out);
}

// Round 6
// 90.844 us; speedup vs baseline: 1.4017x; 1.4017x over previous
//
#include <hip/hip_runtime.h>
#include <stdint.h>

#define EPS_BN 1e-5f

#define C 256
#define H 28
#define W 28
#define R196 196
#define M_TOT 12544
#define K1 2304

typedef __attribute__((ext_vector_type(8))) short bf16x8;
typedef __attribute__((ext_vector_type(4))) float f32x4;
typedef __attribute__((ext_vector_type(4))) unsigned short u16x4;
typedef unsigned short ushort_t;

__device__ __forceinline__ unsigned short sgn_bf16(float v) {
    return v > 0.f ? (unsigned short)0x3F80
                   : (v < 0.f ? (unsigned short)0xBF80 : (unsigned short)0);
}

__device__ __forceinline__ void gload16(const void* g, void* l) {
    __builtin_amdgcn_global_load_lds(
        (const __attribute__((address_space(1))) void*)g,
        (__attribute__((address_space(3))) void*)l, 16, 0, 0);
}

// ---------------------------------------------------------------------------
// Kernel 1: weight prep (unchanged).
// ---------------------------------------------------------------------------
__global__ void prep_weights(
    const float* __restrict__ w1,
    const float* __restrict__ bn1_g, const float* __restrict__ bn1_b,
    const float* __restrict__ bn1_m, const float* __restrict__ bn1_v,
    const float* __restrict__ w21,
    const float* __restrict__ bn21_g, const float* __restrict__ bn21_b,
    const float* __restrict__ bn21_m, const float* __restrict__ bn21_v,
    const float* __restrict__ w22,
    const float* __restrict__ bn22_g, const float* __restrict__ bn22_b,
    const float* __restrict__ bn22_m, const float* __restrict__ bn22_v,
    unsigned short* __restrict__ bw1, unsigned short* __restrict__ bw2,
    float* __restrict__ alpha1, float* __restrict__ beta1,
    float* __restrict__ alpha2, float* __restrict__ beta2)
{
    __shared__ float red[256];
    const int bid = blockIdx.x;
    const int t = threadIdx.x;

    if (bid < 256) {
        const int oc = bid;
        const float* w = w1 + oc * K1;
        float s = 0.f;
        for (int i = t; i < K1; i += 256) s += fabsf(w[i]);
        red[t] = s; __syncthreads();
        for (int o = 128; o > 0; o >>= 1) {
            if (t < o) red[t] += red[t + o];
            __syncthreads();
        }
        const float scale = red[0] * (1.f / (float)K1);
        if (t == 0) {
            const float inv = bn1_g[oc] * rsqrtf(bn1_v[oc] + EPS_BN);
            alpha1[oc] = scale * inv;
            beta1[oc]  = bn1_b[oc] - bn1_m[oc] * inv;
        }
        for (int i = t; i < K1; i += 256) {
            const int ic = i / 9, tap = i % 9;
            bw1[(oc * 9 + tap) * 256 + ic] = sgn_bf16(w[i]);
        }
    } else {
        const bool br2 = (bid >= 512);
        const int oc = (bid - 256) & 255;
        const float* w = (br2 ? w22 : w21) + oc * 256;
        red[t] = fabsf(w[t]); __syncthreads();
        for (int o = 128; o > 0; o >>= 1) {
            if (t < o) red[t] += red[t + o];
            __syncthreads();
        }
        const float scale = red[0] * (1.f / 256.f);
        const int n = oc + (br2 ? 256 : 0);
        if (t == 0) {
            const float g = br2 ? bn22_g[oc] : bn21_g[oc];
            const float b = br2 ? bn22_b[oc] : bn21_b[oc];
            const float m = br2 ? bn22_m[oc] : bn21_m[oc];
            const float v = br2 ? bn22_v[oc] : bn21_v[oc];
            const float inv = g * rsqrtf(v + EPS_BN);
            alpha2[n] = scale * inv;
            beta2[n]  = b - m * inv;
        }
        bw2[n * 256 + t] = sgn_bf16(w[t]);
    }
}

// ---------------------------------------------------------------------------
// Kernel 2: fused sign(x+bias) -> a1p AND 2x2 avgpool (unchanged).
// ---------------------------------------------------------------------------
__global__ __launch_bounds__(256) void sign_pool(
    const float* __restrict__ x, const float* __restrict__ bias,
    ushort_t* __restrict__ a1p, float* __restrict__ pool)
{
    __shared__ float lx[2][256][29];
    const int bo = blockIdx.x;               // b*14 + oh
    const int b = bo / 14, oh = bo % 14;
    const int t = threadIdx.x;
    const float* xb = x + (size_t)(b * 256) * 784 + (2 * oh) * 28;

    for (int idx = t; idx < 2 * 28 * 256; idx += 256) {
        const int row = idx / 7168;
        const int rem = idx - row * 7168;
        const int c = rem / 28, iw = rem % 28;
        lx[row][c][iw] = xb[c * 784 + row * 28 + iw];
    }
    __syncthreads();

#pragma unroll
    for (int row = 0; row < 2; ++row) {
        ushort_t* orow = a1p + (size_t)((b * 30 + 2 * oh + row + 1) * 30) * 256;
        for (int idx = t; idx < 28 * 256; idx += 256) {
            const int c = idx & 255, iw = idx >> 8;
            orow[(iw + 1) * 256 + c] = sgn_bf16(lx[row][c][iw] + bias[c]);
        }
        orow[t] = 0;
        orow[29 * 256 + t] = 0;
    }

    for (int idx = t; idx < 256 * 14; idx += 256) {
        const int c = idx / 14, ow = idx % 14;
        pool[(size_t)(b * 256 + c) * 196 + oh * 14 + ow] =
            0.25f * (lx[0][c][2 * ow] + lx[0][c][2 * ow + 1] +
                     lx[1][c][2 * ow] + lx[1][c][2 * ow + 1]);
    }

    if (oh == 0) {
        ushort_t* r0  = a1p + (size_t)(b * 900) * 256;
        ushort_t* r29 = a1p + (size_t)(b * 900 + 29 * 30) * 256;
        for (int idx = t; idx < 30 * 256; idx += 256) { r0[idx] = 0; r29[idx] = 0; }
    }
}

// ---------------------------------------------------------------------------
// Kernel 3: conv1 (3x3 s2) GEMM. BM=64 BN=64 BK=64, 784 blocks (196m x 4n),
// 8 waves (2m x 4n), wave tile 32x16, 512 threads. Depth-2 counted-vmcnt
// pipeline, 32 KB LDS -> ~24 resident waves/CU (2x R4's TLP).
// ---------------------------------------------------------------------------
__global__ __launch_bounds__(512) void conv1_lds(
    const ushort_t* __restrict__ a1p,   // [64][30][30][256]
    const ushort_t* __restrict__ bw1,   // [256][2304]
    const float* __restrict__ alpha1, const float* __restrict__ beta1,
    const float* __restrict__ p,
    const float* __restrict__ rsb,
    const float* __restrict__ prg, const float* __restrict__ prb,
    const float* __restrict__ prz,
    float* __restrict__ out2,
    ushort_t* __restrict__ a2)
{
    __shared__ ushort_t lA[2][64 * 64];
    __shared__ ushort_t lB[2][64 * 64];

    const int bid = blockIdx.x;
    const int wgid = (bid & 7) * 98 + (bid >> 3);   // 784 = 8*98
    const int mtile = wgid >> 2;        // 0..195 (ntile fastest -> same XCD)
    const int ntile = wgid & 3;

    const int tid = threadIdx.x;
    const int wave = tid >> 6;          // 0..7
    const int lane = tid & 63;
    const int col = lane & 15;
    const int krow = lane >> 4;
    const int wr = wave >> 2;           // 0..1: m half (32 rows)
    const int wc = wave & 3;            // 0..3: n quarter (16 cols)
    const int l8 = lane >> 3;           // row-within-8
    const int s8 = lane & 7;            // slot
    const int swz = ((s8 ^ l8) << 3);   // pre-swizzled source column (elements)

    // staging: wave handles rows [wave*8, wave*8+8) of A and of B (1 gload each)
    int pbA;
    {
        const int grow = wave * 8 + l8;
        const int m = mtile * 64 + grow;
        const int b = m / 196, r = m % 196;
        const int oh = r / 14, ow = r % 14;
        pbA = ((b * 30 + 2 * oh) * 30 + 2 * ow) * 256 + swz;
    }
    const int pbB = (ntile * 64 + wave * 8 + l8) * K1 + swz;

    int rswz[2];
#pragma unroll
    for (int ks = 0; ks < 2; ++ks)
        rswz[ks] = ((ks * 4 + krow) ^ (col & 7)) << 4;

    f32x4 acc[2] = {};

    auto stage = [&](int step, int buf) {
        const int tap = step >> 2;
        const int kc0 = (step & 3) << 6;
        const int kh = tap / 3, kw = tap - kh * 3;
        const int aoff = (kh * 30 + kw) * 256 + kc0;
        gload16(a1p + pbA + aoff, (char*)&lA[buf][0] + (wave * 8) * 128);
        gload16(bw1 + pbB + step * 64, (char*)&lB[buf][0] + (wave * 8) * 128);
    };

    stage(0, 0);

    int cur = 0;
    for (int step = 0; step < 36; ++step) {
        if (step + 1 < 36) {
            stage(step + 1, cur ^ 1);                        // 2 new loads in flight
            asm volatile("s_waitcnt vmcnt(2)" ::: "memory"); // tile-t's 2 done
        } else {
            asm volatile("s_waitcnt vmcnt(0)" ::: "memory");
        }
        __builtin_amdgcn_s_barrier();        // all waves' tile-t loads landed
        __builtin_amdgcn_sched_barrier(0);

#pragma unroll
        for (int ks = 0; ks < 2; ++ks) {
            bf16x8 bf[2], af;
#pragma unroll
            for (int im = 0; im < 2; ++im) {
                const int row = wr * 32 + im * 16 + col;
                bf[im] = *(const bf16x8*)((const char*)&lA[cur][0] + row * 128 + rswz[ks]);
            }
            {
                const int row = wc * 16 + col;
                af = *(const bf16x8*)((const char*)&lB[cur][0] + row * 128 + rswz[ks]);
            }
#pragma unroll
            for (int im = 0; im < 2; ++im)
                acc[im] = __builtin_amdgcn_mfma_f32_16x16x32_bf16(
                    af, bf[im], acc[im], 0, 0, 0);
        }
        __builtin_amdgcn_sched_barrier(0);
        __builtin_amdgcn_s_barrier();        // cur fully read -> restageable
        cur ^= 1;
    }

#pragma unroll
    for (int im = 0; im < 2; ++im) {
        const int m = mtile * 64 + wr * 32 + im * 16 + col;
        const int b = m / 196, r = m % 196;
        const int n0 = ntile * 64 + wc * 16 + krow * 4;
        u16x4 spack;
#pragma unroll
        for (int j = 0; j < 4; ++j) {
            const int n = n0 + j;
            const int idx = (b * 256 + n) * 196 + r;
            float v = alpha1[n] * acc[im][j] + beta1[n] + p[idx];
            const float t = v - prg[n];
            const float o = (t > 0.f ? t : prb[n] * t) + prz[n];
            out2[idx] = o;
            spack[j] = sgn_bf16(o + rsb[n]);
        }
        *(u16x4*)(a2 + m * 256 + n0) = spack;
    }
}

// ---------------------------------------------------------------------------
// Kernel 4: both 1x1 convs. BM=64 BN=64 K=256 (4 steps), 1568 blocks
// (196m x 8n), 8 waves, depth-2 counted-vmcnt.
// ---------------------------------------------------------------------------
__global__ __launch_bounds__(512) void conv1x1_lds(
    const ushort_t* __restrict__ a2,
    const ushort_t* __restrict__ bw2,
    const float* __restrict__ alpha2, const float* __restrict__ beta2,
    const float* __restrict__ out2,
    const float* __restrict__ prg, const float* __restrict__ prb,
    const float* __restrict__ prz,
    float* __restrict__ out)
{
    __shared__ ushort_t lA[2][64 * 64];
    __shared__ ushort_t lB[2][64 * 64];

    const int bid = blockIdx.x;
    const int wgid = (bid & 7) * 196 + (bid >> 3);  // 1568 = 8*196
    const int mtile = wgid >> 3;        // 0..195 (ntile fastest)
    const int ntile = wgid & 7;

    const int tid = threadIdx.x;
    const int wave = tid >> 6;
    const int lane = tid & 63;
    const int col = lane & 15;
    const int krow = lane >> 4;
    const int wr = wave >> 2;
    const int wc = wave & 3;
    const int l8 = lane >> 3;
    const int s8 = lane & 7;
    const int swz = ((s8 ^ l8) << 3);

    const int pbA = (mtile * 64 + wave * 8 + l8) * 256 + swz;
    const int pbB = (ntile * 64 + wave * 8 + l8) * 256 + swz;

    int rswz[2];
#pragma unroll
    for (int ks = 0; ks < 2; ++ks)
        rswz[ks] = ((ks * 4 + krow) ^ (col & 7)) << 4;

    f32x4 acc[2] = {};

    auto stage = [&](int step, int buf) {
        gload16(a2 + pbA + step * 64, (char*)&lA[buf][0] + (wave * 8) * 128);
        gload16(bw2 + pbB + step * 64, (char*)&lB[buf][0] + (wave * 8) * 128);
    };

    stage(0, 0);

    int cur = 0;
    for (int step = 0; step < 4; ++step) {
        if (step + 1 < 4) {
            stage(step + 1, cur ^ 1);
            asm volatile("s_waitcnt vmcnt(2)" ::: "memory");
        } else {
            asm volatile("s_waitcnt vmcnt(0)" ::: "memory");
        }
        __builtin_amdgcn_s_barrier();
        __builtin_amdgcn_sched_barrier(0);

#pragma unroll
        for (int ks = 0; ks < 2; ++ks) {
            bf16x8 bf[2], af;
#pragma unroll
            for (int im = 0; im < 2; ++im) {
                const int row = wr * 32 + im * 16 + col;
                bf[im] = *(const bf16x8*)((const char*)&lA[cur][0] + row * 128 + rswz[ks]);
            }
            {
                const int row = wc * 16 + col;
                af = *(const bf16x8*)((const char*)&lB[cur][0] + row * 128 + rswz[ks]);
            }
#pragma unroll
            for (int im = 0; im < 2; ++im)
                acc[im] = __builtin_amdgcn_mfma_f32_16x16x32_bf16(
                    af, bf[im], acc[im], 0, 0, 0);
        }
        __builtin_amdgcn_sched_barrier(0);
        __builtin_amdgcn_s_barrier();
        cur ^= 1;
    }

#pragma unroll
    for (int im = 0; im < 2; ++im) {
        const int m = mtile * 64 + wr * 32 + im * 16 + col;
        const int b = m / 196, r = m % 196;
#pragma unroll
        for (int j = 0; j < 4; ++j) {
            const int n = ntile * 64 + wc * 16 + krow * 4 + j;   // [0,512)
            const int oc = n & 255;
            float v = alpha2[n] * acc[im][j] + beta2[n]
                    + out2[(b * 256 + oc) * 196 + r];
            const float t = v - prg[oc];
            out[(size_t)(b * 512 + n) * 196 + r] =
                (t > 0.f ? t : prb[oc] * t) + prz[oc];
        }
    }
}

// ---------------------------------------------------------------------------
extern "C" void kernel_launch(void* const* d_in, const int* in_sizes, int n_in,
                              void* d_out, int out_size, void* d_ws, size_t ws_size,
                              hipStream_t stream)
{
    (void)in_sizes; (void)n_in; (void)out_size; (void)ws_size;

    const float* x         = (const float*)d_in[0];
    const float* rsign_b   = (const float*)d_in[1];
    const float* w1        = (const float*)d_in[2];
    const float* bn1_g     = (const float*)d_in[3];
    const float* bn1_b     = (const float*)d_in[4];
    const float* bn1_m     = (const float*)d_in[5];
    const float* bn1_v     = (const float*)d_in[6];
    const float* w21       = (const float*)d_in[7];
    const float* bn21_g    = (const float*)d_in[8];
    const float* bn21_b    = (const float*)d_in[9];
    const float* bn21_m    = (const float*)d_in[10];
    const float* bn21_v    = (const float*)d_in[11];
    const float* w22       = (const float*)d_in[12];
    const float* bn22_g    = (const float*)d_in[13];
    const float* bn22_b    = (const float*)d_in[14];
    const float* bn22_m    = (const float*)d_in[15];
    const float* bn22_v    = (const float*)d_in[16];
    const float* pr_gamma  = (const float*)d_in[17];
    const float* pr_beta   = (const float*)d_in[18];
    const float* pr_zeta   = (const float*)d_in[19];

    char* ws = (char*)d_ws;
    size_t off = 0;
    ushort_t* a1p = (ushort_t*)(ws + off); off += (size_t)14745600 * 2;
    ushort_t* bw1 = (ushort_t*)(ws + off); off += (size_t)589824 * 2;
    ushort_t* bw2 = (ushort_t*)(ws + off); off += (size_t)131072 * 2;
    float* pool   = (float*)(ws + off);    off += (size_t)3211264 * 4;
    float* out2   = (float*)(ws + off);    off += (size_t)3211264 * 4;
    ushort_t* a2  = (ushort_t*)(ws + off); off += (size_t)3211264 * 2;
    float* alpha1 = (float*)(ws + off);    off += 1024;
    float* beta1  = (float*)(ws + off);    off += 1024;
    float* alpha2 = (float*)(ws + off);    off += 2048;
    float* beta2  = (float*)(ws + off);    off += 2048;

    prep_weights<<<768, 256, 0, stream>>>(
        w1, bn1_g, bn1_b, bn1_m, bn1_v,
        w21, bn21_g, bn21_b, bn21_m, bn21_v,
        w22, bn22_g, bn22_b, bn22_m, bn22_v,
        bw1, bw2, alpha1, beta1, alpha2, beta2);

    sign_pool<<<64 * 14, 256, 0, stream>>>(x, rsign_b, a1p, pool);

    conv1_lds<<<784, 512, 0, stream>>>(
        a1p, bw1, alpha1, beta1, pool, rsign_b,
        pr_gamma, pr_beta, pr_zeta, out2, a2);

    conv1x1_lds<<<1568, 512, 0, stream>>>(
        a2, bw2, alpha2, beta2, out2,
        pr_gamma, pr_beta, pr_zeta, (float*)d_out);
}